// Round 8
// baseline (122.618 us; speedup 1.0000x reference)
//
#include <hip/hip_runtime.h>
#include <hip/hip_bf16.h>
#include <cmath>

#define BATCH 8
#define ZDIM 512
#define SDIM 256
#define LVL 16
#define TSZ 16384
#define NPIX 65536   // 256*256
#define P2H 2654435761u

typedef __attribute__((ext_vector_type(8))) short bf16x8;
typedef __attribute__((ext_vector_type(4))) float floatx4;
typedef unsigned short ushort_t;

// ws layout per batch (ushort units):
//  f*1024        : frag f hi (f=0..3 layer0 nb; f=4..11 layer1 kf*4+nb)
//  f*1024 + 512  : frag f lo
//  12288 + f2*512: layer2 frag f2 in DIRECT lane order [lane*8+e]
//                  f2 = {0:kf0-hi, 1:kf0-lo, 2:kf1-hi, 3:kf1-lo}
#define BSTRIDE 14336
#define L2OFF 12288
// total ws: 8*14336*2 = 229376 B (proven to fit by R5's ws_size flag)

__device__ __forceinline__ float lrelu(float x) {
    return (x >= 0.0f ? x : 0.2f * x) * 1.41421356237309515f;
}
__device__ __forceinline__ ushort_t f2bf(float x) {   // RNE f32->bf16
    unsigned u = __builtin_bit_cast(unsigned, x);
    u += 0x7fffu + ((u >> 16) & 1u);
    return (ushort_t)(u >> 16);
}
__device__ __forceinline__ float bf2f(ushort_t h) {
    unsigned u = ((unsigned)h) << 16;
    return __builtin_bit_cast(float, u);
}

struct ResPack { float rm1[LVL]; };

__global__ __launch_bounds__(256) void k_setup(
    const float* __restrict__ z,
    const float* __restrict__ w1, const float* __restrict__ b1,
    const float* __restrict__ w2, const float* __restrict__ b2,
    const float* __restrict__ w3, const float* __restrict__ b3,
    const float* __restrict__ gen_w,
    const float* __restrict__ a0w, const float* __restrict__ a0b,
    const float* __restrict__ m0w,
    const float* __restrict__ a1w, const float* __restrict__ a1b,
    const float* __restrict__ m1w,
    const float* __restrict__ a2w, const float* __restrict__ a2b,
    const float* __restrict__ m2w,
    ushort_t* __restrict__ wsf)
{
    const int b = blockIdx.x;
    const int t = threadIdx.x;
    __shared__ float sA[SDIM];
    __shared__ float sB[SDIM];
    __shared__ float zb[ZDIM];
    __shared__ float sc0[32], sc1[64], sc2[64], modv[32];
    __shared__ float d0[64], d1[64], d2[4];
    __shared__ float wl0[32 * 64];
    __shared__ float wl1[64 * 64];
    __shared__ float wl2[64 * 16];

    zb[t]       = z[b * ZDIM + t];
    zb[t + 256] = z[b * ZDIM + 256 + t];
    __syncthreads();

    {
        float a0 = 0.f, a1 = 0.f, a2 = 0.f, a3 = 0.f;
#pragma unroll 8
        for (int k = 0; k < ZDIM; k += 4) {
            a0 = fmaf(zb[k + 0], w1[(k + 0) * SDIM + t], a0);
            a1 = fmaf(zb[k + 1], w1[(k + 1) * SDIM + t], a1);
            a2 = fmaf(zb[k + 2], w1[(k + 2) * SDIM + t], a2);
            a3 = fmaf(zb[k + 3], w1[(k + 3) * SDIM + t], a3);
        }
        sA[t] = lrelu(b1[t] + ((a0 + a1) + (a2 + a3)));
    }
    __syncthreads();
    {
        float a0 = 0.f, a1 = 0.f, a2 = 0.f, a3 = 0.f;
#pragma unroll 8
        for (int k = 0; k < SDIM; k += 4) {
            a0 = fmaf(sA[k + 0], w2[(k + 0) * SDIM + t], a0);
            a1 = fmaf(sA[k + 1], w2[(k + 1) * SDIM + t], a1);
            a2 = fmaf(sA[k + 2], w2[(k + 2) * SDIM + t], a2);
            a3 = fmaf(sA[k + 3], w2[(k + 3) * SDIM + t], a3);
        }
        sB[t] = lrelu(b2[t] + ((a0 + a1) + (a2 + a3)));
    }
    __syncthreads();
    {
        float a0 = 0.f, a1 = 0.f, a2 = 0.f, a3 = 0.f;
#pragma unroll 8
        for (int k = 0; k < SDIM; k += 4) {
            a0 = fmaf(sB[k + 0], w3[(k + 0) * SDIM + t], a0);
            a1 = fmaf(sB[k + 1], w3[(k + 1) * SDIM + t], a1);
            a2 = fmaf(sB[k + 2], w3[(k + 2) * SDIM + t], a2);
            a3 = fmaf(sB[k + 3], w3[(k + 3) * SDIM + t], a3);
        }
        sA[t] = lrelu(b3[t] + ((a0 + a1) + (a2 + a3)));
    }
    __syncthreads();

    if (t < 32) {
        const int l = t >> 1, f = t & 1;
        float m = 0.0f;
        for (int k = 0; k < SDIM; ++k) m = fmaf(sA[k], gen_w[l * (SDIM * 2) + k * 2 + f], m);
        modv[t] = 1.0f + m;
    } else if (t < 64) {
        const int i = t - 32;
        float sc = a0b[i];
        for (int k = 0; k < SDIM; ++k) sc = fmaf(sA[k], a0w[k * 32 + i], sc);
        sc0[i] = sc;
    } else if (t < 128) {
        const int i = t - 64;
        float sc = a1b[i];
        for (int k = 0; k < SDIM; ++k) sc = fmaf(sA[k], a1w[k * 64 + i], sc);
        sc1[i] = sc;
    } else if (t < 192) {
        const int i = t - 128;
        float sc = a2b[i];
        for (int k = 0; k < SDIM; ++k) sc = fmaf(sA[k], a2w[k * 64 + i], sc);
        sc2[i] = sc;
    }
    __syncthreads();

    if (t < 64) {
        float s2 = 0.0f;
        for (int i = 0; i < 32; ++i) { float v = m0w[i * 64 + t] * sc0[i]; s2 = fmaf(v, v, s2); }
        d0[t] = rsqrtf(s2 + 1e-8f);
    } else if (t < 128) {
        const int j = t - 64;
        float s2 = 0.0f;
        for (int i = 0; i < 64; ++i) { float v = m1w[i * 64 + j] * sc1[i]; s2 = fmaf(v, v, s2); }
        d1[j] = rsqrtf(s2 + 1e-8f);
    } else if (t < 131) {
        const int j = t - 128;
        float s2 = 0.0f;
        for (int i = 0; i < 64; ++i) { float v = m2w[i * 3 + j] * sc2[i]; s2 = fmaf(v, v, s2); }
        d2[j] = rsqrtf(s2 + 1e-8f);
    }
    __syncthreads();

    for (int e = t; e < 2048; e += 256) {
        const int i = e >> 6, j = e & 63;
        wl0[e] = m0w[e] * sc0[i] * d0[j] * modv[i];
    }
    for (int e = t; e < 4096; e += 256) {
        const int i = e >> 6, j = e & 63;
        wl1[e] = m1w[e] * sc1[i] * d1[j];
    }
    for (int e = t; e < 1024; e += 256) {
        const int i = e >> 4, j = e & 15;
        wl2[e] = (j < 3) ? m2w[i * 3 + j] * sc2[i] * d2[j] : 0.0f;
    }
    __syncthreads();

    // B-fragments (identity slot map, verified by R5 probe), hi/lo split
    ushort_t* outb = wsf + b * BSTRIDE;
    for (int s = t; s < 768; s += 256) {
        const int f = s >> 6, lane = s & 63;
        const int g = lane >> 4, c = lane & 15;
        bf16x8 hv, lv;
#pragma unroll
        for (int e = 0; e < 8; ++e) {
            float wv;
            if (f < 4) {
                wv = wl0[(g * 8 + e) * 64 + f * 16 + c];
            } else {
                const int kf = (f - 4) >> 2, nb = (f - 4) & 3;
                wv = wl1[(kf * 32 + g * 8 + e) * 64 + nb * 16 + c];
            }
            const ushort_t hh = f2bf(wv);
            hv[e] = (short)hh;
            lv[e] = (short)f2bf(wv - bf2f(hh));
        }
        *(bf16x8*)(outb + f * 1024 + lane * 8) = hv;
        *(bf16x8*)(outb + f * 1024 + 512 + lane * 8) = lv;
    }
    // layer-2 frags in direct lane order -> k_main does 4 x b128 loads
    for (int s = t; s < 2048; s += 256) {
        const int f2 = s >> 9, idx = s & 511;
        const int lane = idx >> 3, e = idx & 7;
        const int g = lane >> 4, c = lane & 15;
        const int kf = f2 >> 1, pl = f2 & 1;
        const float wv = wl2[(kf * 32 + g * 8 + e) * 16 + c];   // 0 for c>=3
        const ushort_t hh = f2bf(wv);
        outb[L2OFF + s] = pl ? f2bf(wv - bf2f(hh)) : hh;
    }
}

// R6 geometry (4 waves, REAL barriers) + R7's reduced-MFMA path.
__global__ __launch_bounds__(256) void k_main(
    const float* __restrict__ base_tables,
    const ushort_t* __restrict__ wsf,
    const float* __restrict__ m0b,
    const float* __restrict__ m1b,
    const float* __restrict__ m2b,
    float* __restrict__ out,
    ResPack rp)
{
    __shared__ ushort_t lds_t[64 * 64];   // per-wave 16-row regions, hi-plane only

    const int t = threadIdx.x;
    const int w = t >> 6;
    const int l = t & 63;
    const int g = l >> 4;
    const int c = l & 15;
    const int tile_base = blockIdx.x * 64 + w * 16;

    // ---- fp32 features for this lane's pixel, all 16 levels (R5-verified path)
    const int apx = tile_base + c;
    const float cx = ((float)(apx & 255) + 0.5f) * (1.0f / 256.0f);
    const float cy = ((float)(apx >> 8) + 0.5f) * (1.0f / 256.0f);
    float rf32[32];
#pragma unroll
    for (int lv = 0; lv < LVL; ++lv) {
        const float r1 = rp.rm1[lv];
        const float sx = cx * r1, sy = cy * r1;
        const float pxf = floorf(sx), pyf = floorf(sy);
        const float fx = sx - pxf, fy = sy - pyf;
        const unsigned x0 = (unsigned)pxf, y0 = (unsigned)pyf;
        const unsigned x1 = x0 + 1u, y1 = y0 + 1u;
        const unsigned hy0 = y0 * P2H, hy1 = y1 * P2H;
        const float2* tab = reinterpret_cast<const float2*>(base_tables) + (lv << 14);
        const float2 f00 = tab[(x0 ^ hy0) & (TSZ - 1)];
        const float2 f01 = tab[(x0 ^ hy1) & (TSZ - 1)];
        const float2 f10 = tab[(x1 ^ hy0) & (TSZ - 1)];
        const float2 f11 = tab[(x1 ^ hy1) & (TSZ - 1)];
        const float w00 = (1.0f - fx) * (1.0f - fy);
        const float w01 = (1.0f - fx) * fy;
        const float w10 = fx * (1.0f - fy);
        const float w11 = fx * fy;
        rf32[2 * lv]     = w00 * f00.x + w01 * f01.x + w10 * f10.x + w11 * f11.x;
        rf32[2 * lv + 1] = w00 * f00.y + w01 * f01.y + w10 * f10.y + w11 * f11.y;
    }
    bf16x8 rf_hi;
#pragma unroll
    for (int e = 0; e < 8; ++e) rf_hi[e] = (short)f2bf(rf32[8 * g + e]);

    // biases (static col map c, verified identity in R5)
    const float b0v[4] = { m0b[c], m0b[16 + c], m0b[32 + c], m0b[48 + c] };
    const float b1v[4] = { m1b[c], m1b[16 + c], m1b[32 + c], m1b[48 + c] };
    const float b2v = (c < 3) ? m2b[c] : 0.0f;

    const int wbase = w * 16;
    const int rpx = wbase + c;
    const int sA0 = rpx * 64 + 8 * (g ^ (c & 7));
    const int sA1 = rpx * 64 + 8 * ((4 + g) ^ (c & 7));

#pragma unroll 1
    for (int b = 0; b < BATCH; ++b) {
        __syncthreads();
        const ushort_t* F = wsf + b * BSTRIDE + l * 8;
        const ushort_t* w2c = wsf + b * BSTRIDE + L2OFF;
#define LDF(fi, which) (*(const bf16x8*)(F + (fi) * 1024 + (which) * 512))

        // ---- layer 0 (a-hi only x W hi+lo)
        floatx4 acc0[4];
#pragma unroll
        for (int nb = 0; nb < 4; ++nb) {
            acc0[nb] = (floatx4){ b0v[nb], b0v[nb], b0v[nb], b0v[nb] };
            acc0[nb] = __builtin_amdgcn_mfma_f32_16x16x32_bf16(rf_hi, LDF(nb, 0), acc0[nb], 0, 0, 0);
            acc0[nb] = __builtin_amdgcn_mfma_f32_16x16x32_bf16(rf_hi, LDF(nb, 1), acc0[nb], 0, 0, 0);
        }
#pragma unroll
        for (int nb = 0; nb < 4; ++nb)
#pragma unroll
            for (int q = 0; q < 4; ++q) {
                const int p = 4 * g + q;
                const int sw = (16 * nb + c) ^ (8 * (p & 7));
                lds_t[(wbase + p) * 64 + sw] = f2bf(lrelu(acc0[nb][q]));
            }
        __syncthreads();
        const bf16x8 a1h0 = *(const bf16x8*)(lds_t + sA0);
        const bf16x8 a1h1 = *(const bf16x8*)(lds_t + sA1);

        // ---- layer 1
        floatx4 acc1[4];
#pragma unroll
        for (int nb = 0; nb < 4; ++nb) {
            acc1[nb] = (floatx4){ b1v[nb], b1v[nb], b1v[nb], b1v[nb] };
            acc1[nb] = __builtin_amdgcn_mfma_f32_16x16x32_bf16(a1h0, LDF(4 + nb, 0), acc1[nb], 0, 0, 0);
            acc1[nb] = __builtin_amdgcn_mfma_f32_16x16x32_bf16(a1h0, LDF(4 + nb, 1), acc1[nb], 0, 0, 0);
            acc1[nb] = __builtin_amdgcn_mfma_f32_16x16x32_bf16(a1h1, LDF(8 + nb, 0), acc1[nb], 0, 0, 0);
            acc1[nb] = __builtin_amdgcn_mfma_f32_16x16x32_bf16(a1h1, LDF(8 + nb, 1), acc1[nb], 0, 0, 0);
        }
        __syncthreads();
#pragma unroll
        for (int nb = 0; nb < 4; ++nb)
#pragma unroll
            for (int q = 0; q < 4; ++q) {
                const int p = 4 * g + q;
                const int sw = (16 * nb + c) ^ (8 * (p & 7));
                lds_t[(wbase + p) * 64 + sw] = f2bf(lrelu(acc1[nb][q]));
            }
        __syncthreads();
        const bf16x8 a2h0 = *(const bf16x8*)(lds_t + sA0);
        const bf16x8 a2h1 = *(const bf16x8*)(lds_t + sA1);

        // ---- layer 2 (direct-order frags: 4 x b128)
        const bf16x8 w2h0 = *(const bf16x8*)(w2c + 0 * 512 + l * 8);
        const bf16x8 w2l0 = *(const bf16x8*)(w2c + 1 * 512 + l * 8);
        const bf16x8 w2h1 = *(const bf16x8*)(w2c + 2 * 512 + l * 8);
        const bf16x8 w2l1 = *(const bf16x8*)(w2c + 3 * 512 + l * 8);
        floatx4 acc2 = (floatx4){ b2v, b2v, b2v, b2v };
        acc2 = __builtin_amdgcn_mfma_f32_16x16x32_bf16(a2h0, w2h0, acc2, 0, 0, 0);
        acc2 = __builtin_amdgcn_mfma_f32_16x16x32_bf16(a2h0, w2l0, acc2, 0, 0, 0);
        acc2 = __builtin_amdgcn_mfma_f32_16x16x32_bf16(a2h1, w2h1, acc2, 0, 0, 0);
        acc2 = __builtin_amdgcn_mfma_f32_16x16x32_bf16(a2h1, w2l1, acc2, 0, 0, 0);

        // store (static verified map: reg q -> row 4g+q, col c)
        if (c < 3) {
            *(floatx4*)(out + (b * 3 + c) * NPIX + tile_base + 4 * g) = acc2;
        }
#undef LDF
    }
}

extern "C" void kernel_launch(void* const* d_in, const int* in_sizes, int n_in,
                              void* d_out, int out_size, void* d_ws, size_t ws_size,
                              hipStream_t stream) {
    const float* z    = (const float*)d_in[0];
    const float* w1   = (const float*)d_in[1];
    const float* b1   = (const float*)d_in[2];
    const float* w2   = (const float*)d_in[3];
    const float* b2   = (const float*)d_in[4];
    const float* w3   = (const float*)d_in[5];
    const float* b3   = (const float*)d_in[6];
    const float* bt   = (const float*)d_in[7];
    const float* genw = (const float*)d_in[8];
    const float* a0w  = (const float*)d_in[9];
    const float* a0b  = (const float*)d_in[10];
    const float* m0w  = (const float*)d_in[11];
    const float* m0b  = (const float*)d_in[12];
    const float* a1w  = (const float*)d_in[13];
    const float* a1b  = (const float*)d_in[14];
    const float* m1w  = (const float*)d_in[15];
    const float* m1b  = (const float*)d_in[16];
    const float* a2w  = (const float*)d_in[17];
    const float* a2b  = (const float*)d_in[18];
    const float* m2w  = (const float*)d_in[19];
    const float* m2b  = (const float*)d_in[20];
    ushort_t* wsf = (ushort_t*)d_ws;
    float* out = (float*)d_out;

    ResPack rp;
    const double bfac = exp((log(256.0) - log(16.0)) / 15.0);
    for (int lv = 0; lv < LVL; ++lv) {
        const double v = floor(16.0 * pow(bfac, (double)lv));
        rp.rm1[lv] = (float)v - 1.0f;
    }

    hipLaunchKernelGGL(k_setup, dim3(BATCH), dim3(256), 0, stream,
                       z, w1, b1, w2, b2, w3, b3, genw,
                       a0w, a0b, m0w, a1w, a1b, m1w, a2w, a2b, m2w, wsf);

    hipLaunchKernelGGL(k_main, dim3(NPIX / 64), dim3(256), 0, stream,
                       bt, wsf, m0b, m1b, m2b, out, rp);
}

// Round 12
// 62.354 us; speedup vs baseline: 1.9665x; 1.9665x over previous
//
#include <hip/hip_runtime.h>
#include <hip/hip_bf16.h>
#include <cmath>

#define BATCH 8
#define ZDIM 512
#define SDIM 256
#define LVL 16
#define TSZ 16384
#define NPIX 65536   // 256*256
#define P2H 2654435761u

typedef __attribute__((ext_vector_type(8))) short bf16x8;
typedef __attribute__((ext_vector_type(4))) float floatx4;
typedef unsigned short ushort_t;

// ws layout per batch (ushort units): 14 A-frags (weightsᵀ), hi at f*1024+lane*8,
// lo at +512.  f=0..3: W0ᵀ m-blocks.  f=4+2m'+kf: W1ᵀ.  f=12+kf: W2ᵀ.
// Output-channel permutation baked in: ch(m,r) = 8*(r>>2)+(r&3)+4*(m&1)+32*(m>>1)
// so each layer's C-layout output is lane-local for the next layer's B-frag.
#define BSTRIDE 14336
// total ws: 8*14336*2 = 229376 B (fits; proven by R5 ws_size flag)

__device__ __forceinline__ float lrelu(float x) {
    return (x >= 0.0f ? x : 0.2f * x) * 1.41421356237309515f;
}
__device__ __forceinline__ ushort_t f2bf(float x) {   // RNE f32->bf16
    unsigned u = __builtin_bit_cast(unsigned, x);
    u += 0x7fffu + ((u >> 16) & 1u);
    return (ushort_t)(u >> 16);
}
__device__ __forceinline__ float bf2f(ushort_t h) {
    unsigned u = ((unsigned)h) << 16;
    return __builtin_bit_cast(float, u);
}

struct ResPack { float rm1[LVL]; };

__global__ __launch_bounds__(256) void k_setup(
    const float* __restrict__ z,
    const float* __restrict__ w1, const float* __restrict__ b1,
    const float* __restrict__ w2, const float* __restrict__ b2,
    const float* __restrict__ w3, const float* __restrict__ b3,
    const float* __restrict__ gen_w,
    const float* __restrict__ a0w, const float* __restrict__ a0b,
    const float* __restrict__ m0w,
    const float* __restrict__ a1w, const float* __restrict__ a1b,
    const float* __restrict__ m1w,
    const float* __restrict__ a2w, const float* __restrict__ a2b,
    const float* __restrict__ m2w,
    ushort_t* __restrict__ wsf)
{
    const int b = blockIdx.x;
    const int t = threadIdx.x;
    __shared__ float sA[SDIM];
    __shared__ float sB[SDIM];
    __shared__ float zb[ZDIM];
    __shared__ float sc0[32], sc1[64], sc2[64], modv[32];
    __shared__ float d0[64], d1[64], d2[4];
    __shared__ float wl0[32 * 64];
    __shared__ float wl1[64 * 64];
    __shared__ float wl2[64 * 16];

    zb[t]       = z[b * ZDIM + t];
    zb[t + 256] = z[b * ZDIM + 256 + t];
    __syncthreads();

    {
        float a0 = 0.f, a1 = 0.f, a2 = 0.f, a3 = 0.f;
#pragma unroll 8
        for (int k = 0; k < ZDIM; k += 4) {
            a0 = fmaf(zb[k + 0], w1[(k + 0) * SDIM + t], a0);
            a1 = fmaf(zb[k + 1], w1[(k + 1) * SDIM + t], a1);
            a2 = fmaf(zb[k + 2], w1[(k + 2) * SDIM + t], a2);
            a3 = fmaf(zb[k + 3], w1[(k + 3) * SDIM + t], a3);
        }
        sA[t] = lrelu(b1[t] + ((a0 + a1) + (a2 + a3)));
    }
    __syncthreads();
    {
        float a0 = 0.f, a1 = 0.f, a2 = 0.f, a3 = 0.f;
#pragma unroll 8
        for (int k = 0; k < SDIM; k += 4) {
            a0 = fmaf(sA[k + 0], w2[(k + 0) * SDIM + t], a0);
            a1 = fmaf(sA[k + 1], w2[(k + 1) * SDIM + t], a1);
            a2 = fmaf(sA[k + 2], w2[(k + 2) * SDIM + t], a2);
            a3 = fmaf(sA[k + 3], w2[(k + 3) * SDIM + t], a3);
        }
        sB[t] = lrelu(b2[t] + ((a0 + a1) + (a2 + a3)));
    }
    __syncthreads();
    {
        float a0 = 0.f, a1 = 0.f, a2 = 0.f, a3 = 0.f;
#pragma unroll 8
        for (int k = 0; k < SDIM; k += 4) {
            a0 = fmaf(sB[k + 0], w3[(k + 0) * SDIM + t], a0);
            a1 = fmaf(sB[k + 1], w3[(k + 1) * SDIM + t], a1);
            a2 = fmaf(sB[k + 2], w3[(k + 2) * SDIM + t], a2);
            a3 = fmaf(sB[k + 3], w3[(k + 3) * SDIM + t], a3);
        }
        sA[t] = lrelu(b3[t] + ((a0 + a1) + (a2 + a3)));
    }
    __syncthreads();

    if (t < 32) {
        const int l = t >> 1, f = t & 1;
        float m = 0.0f;
        for (int k = 0; k < SDIM; ++k) m = fmaf(sA[k], gen_w[l * (SDIM * 2) + k * 2 + f], m);
        modv[t] = 1.0f + m;
    } else if (t < 64) {
        const int i = t - 32;
        float sc = a0b[i];
        for (int k = 0; k < SDIM; ++k) sc = fmaf(sA[k], a0w[k * 32 + i], sc);
        sc0[i] = sc;
    } else if (t < 128) {
        const int i = t - 64;
        float sc = a1b[i];
        for (int k = 0; k < SDIM; ++k) sc = fmaf(sA[k], a1w[k * 64 + i], sc);
        sc1[i] = sc;
    } else if (t < 192) {
        const int i = t - 128;
        float sc = a2b[i];
        for (int k = 0; k < SDIM; ++k) sc = fmaf(sA[k], a2w[k * 64 + i], sc);
        sc2[i] = sc;
    }
    __syncthreads();

    if (t < 64) {
        float s2 = 0.0f;
        for (int i = 0; i < 32; ++i) { float v = m0w[i * 64 + t] * sc0[i]; s2 = fmaf(v, v, s2); }
        d0[t] = rsqrtf(s2 + 1e-8f);
    } else if (t < 128) {
        const int j = t - 64;
        float s2 = 0.0f;
        for (int i = 0; i < 64; ++i) { float v = m1w[i * 64 + j] * sc1[i]; s2 = fmaf(v, v, s2); }
        d1[j] = rsqrtf(s2 + 1e-8f);
    } else if (t < 131) {
        const int j = t - 128;
        float s2 = 0.0f;
        for (int i = 0; i < 64; ++i) { float v = m2w[i * 3 + j] * sc2[i]; s2 = fmaf(v, v, s2); }
        d2[j] = rsqrtf(s2 + 1e-8f);
    }
    __syncthreads();

    for (int e = t; e < 2048; e += 256) {
        const int i = e >> 6, j = e & 63;
        wl0[e] = m0w[e] * sc0[i] * d0[j] * modv[i];
    }
    for (int e = t; e < 4096; e += 256) {
        const int i = e >> 6, j = e & 63;
        wl1[e] = m1w[e] * sc1[i] * d1[j];
    }
    for (int e = t; e < 1024; e += 256) {
        const int i = e >> 4, j = e & 15;
        wl2[e] = (j < 3) ? m2w[i * 3 + j] * sc2[i] * d2[j] : 0.0f;
    }
    __syncthreads();

    // Pack Wᵀ A-fragments (A[row=lane&15][k=8*(lane>>4)+e], R5-verified layout),
    // hi/lo split, with the output-channel permutation ch(m, row).
    ushort_t* outb = wsf + b * BSTRIDE;
    for (int s = t; s < 896; s += 256) {
        const int f = s >> 6, lane = s & 63;
        const int gg = lane >> 4, cc = lane & 15;   // cc = A row, k = 8*gg+e
        bf16x8 hv, lv;
#pragma unroll
        for (int e = 0; e < 8; ++e) {
            float wv;
            if (f < 4) {
                const int m = f;
                const int ch = 8 * (cc >> 2) + (cc & 3) + 4 * (m & 1) + 32 * (m >> 1);
                wv = wl0[(8 * gg + e) * 64 + ch];
            } else if (f < 12) {
                const int m = (f - 4) >> 1, kf = (f - 4) & 1;
                const int ch = 8 * (cc >> 2) + (cc & 3) + 4 * (m & 1) + 32 * (m >> 1);
                wv = wl1[(32 * kf + 8 * gg + e) * 64 + ch];
            } else {
                const int kf = f - 12;
                wv = wl2[(32 * kf + 8 * gg + e) * 16 + cc];   // out=cc, 0-padded cc>=3
            }
            const ushort_t hh = f2bf(wv);
            hv[e] = (short)hh;
            lv[e] = (short)f2bf(wv - bf2f(hh));
        }
        *(bf16x8*)(outb + f * 1024 + lane * 8) = hv;
        *(bf16x8*)(outb + f * 1024 + 512 + lane * 8) = lv;
    }
}

// Swapped-operand MFMA chain: D = Wᵀ·Hᵀ per layer. No LDS, no barriers —
// layer transitions are pure in-register repacks (channel permutation makes
// each layer's output lane-local for the next layer's B-frag).
__global__ __launch_bounds__(256) void k_main(
    const float* __restrict__ base_tables,
    const ushort_t* __restrict__ wsf,
    const float* __restrict__ m0b,
    const float* __restrict__ m1b,
    const float* __restrict__ m2b,
    float* __restrict__ out,
    ResPack rp)
{
    const int t = threadIdx.x;
    const int w = t >> 6;
    const int l = t & 63;
    const int g = l >> 4;
    const int c = l & 15;
    const int tile_base = blockIdx.x * 64 + w * 16;

    // ---- features: lane (g,c) needs levels 4g..4g+3 of pixel tile_base+c.
    // rf_hi = B-frag for layer 0: B[k=8g+e][col=c] = feat[c][8g+e]. (R5-verified)
    const int apx = tile_base + c;
    const float cx = ((float)(apx & 255) + 0.5f) * (1.0f / 256.0f);
    const float cy = ((float)(apx >> 8) + 0.5f) * (1.0f / 256.0f);
    bf16x8 rf_hi;
#pragma unroll
    for (int d = 0; d < 4; ++d) {
        float r1 = rp.rm1[d];
        r1 = (g == 1) ? rp.rm1[4 + d] : r1;
        r1 = (g == 2) ? rp.rm1[8 + d] : r1;
        r1 = (g == 3) ? rp.rm1[12 + d] : r1;
        const float sx = cx * r1, sy = cy * r1;
        const float pxf = floorf(sx), pyf = floorf(sy);
        const float fx = sx - pxf, fy = sy - pyf;
        const unsigned x0 = (unsigned)pxf, y0 = (unsigned)pyf;
        const unsigned x1 = x0 + 1u, y1 = y0 + 1u;
        const unsigned hy0 = y0 * P2H, hy1 = y1 * P2H;
        const float2* tab = reinterpret_cast<const float2*>(base_tables) + ((4 * g + d) << 14);
        const float2 f00 = tab[(x0 ^ hy0) & (TSZ - 1)];
        const float2 f01 = tab[(x0 ^ hy1) & (TSZ - 1)];
        const float2 f10 = tab[(x1 ^ hy0) & (TSZ - 1)];
        const float2 f11 = tab[(x1 ^ hy1) & (TSZ - 1)];
        const float w00 = (1.0f - fx) * (1.0f - fy);
        const float w01 = (1.0f - fx) * fy;
        const float w10 = fx * (1.0f - fy);
        const float w11 = fx * fy;
        const float v0 = w00 * f00.x + w01 * f01.x + w10 * f10.x + w11 * f11.x;
        const float v1 = w00 * f00.y + w01 * f01.y + w10 * f10.y + w11 * f11.y;
        rf_hi[2 * d]     = (short)f2bf(v0);
        rf_hi[2 * d + 1] = (short)f2bf(v1);
    }

    // ---- biases at permuted channel ch(m,4g+q) = 8g+q+4(m&1)+32(m>>1)
    float b0v[4][4], b1v[4][4];
#pragma unroll
    for (int m = 0; m < 4; ++m)
#pragma unroll
        for (int q = 0; q < 4; ++q) {
            const int ch = 8 * g + q + 4 * (m & 1) + 32 * (m >> 1);
            b0v[m][q] = m0b[ch];
            b1v[m][q] = m1b[ch];
        }
    const floatx4 acc2init = (g == 0)
        ? (floatx4){ m2b[0], m2b[1], m2b[2], 0.0f }
        : (floatx4){ 0.0f, 0.0f, 0.0f, 0.0f };

#pragma unroll 1
    for (int b = 0; b < BATCH; ++b) {
        const ushort_t* F = wsf + b * BSTRIDE + l * 8;
#define LDF(fi, which) (*(const bf16x8*)(F + (fi) * 1024 + (which) * 512))

        // ---- layer 0: D0_m = W0ᵀ_m · featᵀ  (K=32; W hi+lo, act hi)
        floatx4 acc0[4];
#pragma unroll
        for (int m = 0; m < 4; ++m) {
            acc0[m] = (floatx4){ b0v[m][0], b0v[m][1], b0v[m][2], b0v[m][3] };
            acc0[m] = __builtin_amdgcn_mfma_f32_16x16x32_bf16(LDF(m, 0), rf_hi, acc0[m], 0, 0, 0);
            acc0[m] = __builtin_amdgcn_mfma_f32_16x16x32_bf16(LDF(m, 1), rf_hi, acc0[m], 0, 0, 0);
        }
        // lrelu + repack: lane holds h0[c][8g+e] (m 0..1) and h0[c][32+8g+e] (m 2..3)
        bf16x8 h1f0, h1f1;
#pragma unroll
        for (int e = 0; e < 8; ++e) {
            h1f0[e] = (short)f2bf(lrelu(acc0[e >> 2][e & 3]));
            h1f1[e] = (short)f2bf(lrelu(acc0[2 + (e >> 2)][e & 3]));
        }

        // ---- layer 1: D1_m = W1ᵀ_m · h0ᵀ  (K=64 = 2 kfrags)
        floatx4 acc1[4];
#pragma unroll
        for (int m = 0; m < 4; ++m) {
            acc1[m] = (floatx4){ b1v[m][0], b1v[m][1], b1v[m][2], b1v[m][3] };
            acc1[m] = __builtin_amdgcn_mfma_f32_16x16x32_bf16(LDF(4 + 2 * m, 0), h1f0, acc1[m], 0, 0, 0);
            acc1[m] = __builtin_amdgcn_mfma_f32_16x16x32_bf16(LDF(4 + 2 * m, 1), h1f0, acc1[m], 0, 0, 0);
            acc1[m] = __builtin_amdgcn_mfma_f32_16x16x32_bf16(LDF(5 + 2 * m, 0), h1f1, acc1[m], 0, 0, 0);
            acc1[m] = __builtin_amdgcn_mfma_f32_16x16x32_bf16(LDF(5 + 2 * m, 1), h1f1, acc1[m], 0, 0, 0);
        }
        bf16x8 h2f0, h2f1;
#pragma unroll
        for (int e = 0; e < 8; ++e) {
            h2f0[e] = (short)f2bf(lrelu(acc1[e >> 2][e & 3]));
            h2f1[e] = (short)f2bf(lrelu(acc1[2 + (e >> 2)][e & 3]));
        }

        // ---- layer 2: D2 = W2ᵀ · h1ᵀ (rows 0..2 real, rest zero-padded)
        floatx4 acc2 = acc2init;
        acc2 = __builtin_amdgcn_mfma_f32_16x16x32_bf16(LDF(12, 0), h2f0, acc2, 0, 0, 0);
        acc2 = __builtin_amdgcn_mfma_f32_16x16x32_bf16(LDF(12, 1), h2f0, acc2, 0, 0, 0);
        acc2 = __builtin_amdgcn_mfma_f32_16x16x32_bf16(LDF(13, 0), h2f1, acc2, 0, 0, 0);
        acc2 = __builtin_amdgcn_mfma_f32_16x16x32_bf16(LDF(13, 1), h2f1, acc2, 0, 0, 0);

        // store: lane (0,c) holds out channels 0..2 (rows q) of pixel tile_base+c
        if (g == 0) {
            out[(b * 3 + 0) * NPIX + tile_base + c] = acc2[0];
            out[(b * 3 + 1) * NPIX + tile_base + c] = acc2[1];
            out[(b * 3 + 2) * NPIX + tile_base + c] = acc2[2];
        }
#undef LDF
    }
}

extern "C" void kernel_launch(void* const* d_in, const int* in_sizes, int n_in,
                              void* d_out, int out_size, void* d_ws, size_t ws_size,
                              hipStream_t stream) {
    const float* z    = (const float*)d_in[0];
    const float* w1   = (const float*)d_in[1];
    const float* b1   = (const float*)d_in[2];
    const float* w2   = (const float*)d_in[3];
    const float* b2   = (const float*)d_in[4];
    const float* w3   = (const float*)d_in[5];
    const float* b3   = (const float*)d_in[6];
    const float* bt   = (const float*)d_in[7];
    const float* genw = (const float*)d_in[8];
    const float* a0w  = (const float*)d_in[9];
    const float* a0b  = (const float*)d_in[10];
    const float* m0w  = (const float*)d_in[11];
    const float* m0b  = (const float*)d_in[12];
    const float* a1w  = (const float*)d_in[13];
    const float* a1b  = (const float*)d_in[14];
    const float* m1w  = (const float*)d_in[15];
    const float* m1b  = (const float*)d_in[16];
    const float* a2w  = (const float*)d_in[17];
    const float* a2b  = (const float*)d_in[18];
    const float* m2w  = (const float*)d_in[19];
    const float* m2b  = (const float*)d_in[20];
    ushort_t* wsf = (ushort_t*)d_ws;
    float* out = (float*)d_out;

    ResPack rp;
    const double bfac = exp((log(256.0) - log(16.0)) / 15.0);
    for (int lv = 0; lv < LVL; ++lv) {
        const double v = floor(16.0 * pow(bfac, (double)lv));
        rp.rm1[lv] = (float)v - 1.0f;
    }

    hipLaunchKernelGGL(k_setup, dim3(BATCH), dim3(256), 0, stream,
                       z, w1, b1, w2, b2, w3, b3, genw,
                       a0w, a0b, m0w, a1w, a1b, m1w, a2w, a2b, m2w, wsf);

    hipLaunchKernelGGL(k_main, dim3(NPIX / 64), dim3(256), 0, stream,
                       bt, wsf, m0b, m1b, m2b, out, rp);
}

// Round 13
// 60.272 us; speedup vs baseline: 2.0344x; 1.0346x over previous
//
#include <hip/hip_runtime.h>
#include <hip/hip_bf16.h>
#include <cmath>

#define BATCH 8
#define ZDIM 512
#define SDIM 256
#define LVL 16
#define TSZ 16384
#define NPIX 65536   // 256*256
#define P2H 2654435761u

typedef __attribute__((ext_vector_type(8))) short bf16x8;
typedef __attribute__((ext_vector_type(4))) float floatx4;
typedef unsigned short ushort_t;

// ws layout per batch (ushort units): 14 A-frags (weightsᵀ), hi at f*1024+lane*8,
// lo at +512.  f=0..3: W0ᵀ m-blocks.  f=4+2m'+kf: W1ᵀ.  f=12+kf: W2ᵀ.
// Output-channel permutation baked in: ch(m,r) = 8*(r>>2)+(r&3)+4*(m&1)+32*(m>>1)
// so each layer's C-layout output is lane-local for the next layer's B-frag.
#define BSTRIDE 14336
// total ws: 8*14336*2 = 229376 B (fits; proven by R5 ws_size flag)

__device__ __forceinline__ float lrelu(float x) {
    return (x >= 0.0f ? x : 0.2f * x) * 1.41421356237309515f;
}
__device__ __forceinline__ ushort_t f2bf(float x) {   // RNE f32->bf16
    unsigned u = __builtin_bit_cast(unsigned, x);
    u += 0x7fffu + ((u >> 16) & 1u);
    return (ushort_t)(u >> 16);
}
__device__ __forceinline__ float bf2f(ushort_t h) {
    unsigned u = ((unsigned)h) << 16;
    return __builtin_bit_cast(float, u);
}

struct ResPack { float rm1[LVL]; };

__global__ __launch_bounds__(256) void k_setup(
    const float* __restrict__ z,
    const float* __restrict__ w1, const float* __restrict__ b1,
    const float* __restrict__ w2, const float* __restrict__ b2,
    const float* __restrict__ w3, const float* __restrict__ b3,
    const float* __restrict__ gen_w,
    const float* __restrict__ a0w, const float* __restrict__ a0b,
    const float* __restrict__ m0w,
    const float* __restrict__ a1w, const float* __restrict__ a1b,
    const float* __restrict__ m1w,
    const float* __restrict__ a2w, const float* __restrict__ a2b,
    const float* __restrict__ m2w,
    ushort_t* __restrict__ wsf)
{
    const int b = blockIdx.x;
    const int t = threadIdx.x;
    __shared__ float sA[SDIM];
    __shared__ float sB[SDIM];
    __shared__ float zb[ZDIM];
    __shared__ float sc0[32], sc1[64], sc2[64], modv[32];
    __shared__ float d0[64], d1[64], d2[4];
    __shared__ float wl0[32 * 64];
    __shared__ float wl1[64 * 64];
    __shared__ float wl2[64 * 16];

    zb[t]       = z[b * ZDIM + t];
    zb[t + 256] = z[b * ZDIM + 256 + t];
    __syncthreads();

    {
        float a0 = 0.f, a1 = 0.f, a2 = 0.f, a3 = 0.f;
#pragma unroll 8
        for (int k = 0; k < ZDIM; k += 4) {
            a0 = fmaf(zb[k + 0], w1[(k + 0) * SDIM + t], a0);
            a1 = fmaf(zb[k + 1], w1[(k + 1) * SDIM + t], a1);
            a2 = fmaf(zb[k + 2], w1[(k + 2) * SDIM + t], a2);
            a3 = fmaf(zb[k + 3], w1[(k + 3) * SDIM + t], a3);
        }
        sA[t] = lrelu(b1[t] + ((a0 + a1) + (a2 + a3)));
    }
    __syncthreads();
    {
        float a0 = 0.f, a1 = 0.f, a2 = 0.f, a3 = 0.f;
#pragma unroll 8
        for (int k = 0; k < SDIM; k += 4) {
            a0 = fmaf(sA[k + 0], w2[(k + 0) * SDIM + t], a0);
            a1 = fmaf(sA[k + 1], w2[(k + 1) * SDIM + t], a1);
            a2 = fmaf(sA[k + 2], w2[(k + 2) * SDIM + t], a2);
            a3 = fmaf(sA[k + 3], w2[(k + 3) * SDIM + t], a3);
        }
        sB[t] = lrelu(b2[t] + ((a0 + a1) + (a2 + a3)));
    }
    __syncthreads();
    {
        float a0 = 0.f, a1 = 0.f, a2 = 0.f, a3 = 0.f;
#pragma unroll 8
        for (int k = 0; k < SDIM; k += 4) {
            a0 = fmaf(sB[k + 0], w3[(k + 0) * SDIM + t], a0);
            a1 = fmaf(sB[k + 1], w3[(k + 1) * SDIM + t], a1);
            a2 = fmaf(sB[k + 2], w3[(k + 2) * SDIM + t], a2);
            a3 = fmaf(sB[k + 3], w3[(k + 3) * SDIM + t], a3);
        }
        sA[t] = lrelu(b3[t] + ((a0 + a1) + (a2 + a3)));
    }
    __syncthreads();

    // scale/demod GEMVs — 4-accumulator ILP (was single-acc serial chains,
    // the latency bottleneck per R12 counters: VALUBusy 0.3%)
    if (t < 32) {
        const int l = t >> 1, f = t & 1;
        const float* gw = gen_w + l * (SDIM * 2) + f;
        float a0 = 0.f, a1 = 0.f, a2 = 0.f, a3 = 0.f;
#pragma unroll 8
        for (int k = 0; k < SDIM; k += 4) {
            a0 = fmaf(sA[k + 0], gw[(k + 0) * 2], a0);
            a1 = fmaf(sA[k + 1], gw[(k + 1) * 2], a1);
            a2 = fmaf(sA[k + 2], gw[(k + 2) * 2], a2);
            a3 = fmaf(sA[k + 3], gw[(k + 3) * 2], a3);
        }
        modv[t] = 1.0f + ((a0 + a1) + (a2 + a3));
    } else if (t < 64) {
        const int i = t - 32;
        float a0 = 0.f, a1 = 0.f, a2 = 0.f, a3 = 0.f;
#pragma unroll 8
        for (int k = 0; k < SDIM; k += 4) {
            a0 = fmaf(sA[k + 0], a0w[(k + 0) * 32 + i], a0);
            a1 = fmaf(sA[k + 1], a0w[(k + 1) * 32 + i], a1);
            a2 = fmaf(sA[k + 2], a0w[(k + 2) * 32 + i], a2);
            a3 = fmaf(sA[k + 3], a0w[(k + 3) * 32 + i], a3);
        }
        sc0[i] = a0b[i] + ((a0 + a1) + (a2 + a3));
    } else if (t < 128) {
        const int i = t - 64;
        float a0 = 0.f, a1 = 0.f, a2 = 0.f, a3 = 0.f;
#pragma unroll 8
        for (int k = 0; k < SDIM; k += 4) {
            a0 = fmaf(sA[k + 0], a1w[(k + 0) * 64 + i], a0);
            a1 = fmaf(sA[k + 1], a1w[(k + 1) * 64 + i], a1);
            a2 = fmaf(sA[k + 2], a1w[(k + 2) * 64 + i], a2);
            a3 = fmaf(sA[k + 3], a1w[(k + 3) * 64 + i], a3);
        }
        sc1[i] = a1b[i] + ((a0 + a1) + (a2 + a3));
    } else if (t < 192) {
        const int i = t - 128;
        float a0 = 0.f, a1 = 0.f, a2 = 0.f, a3 = 0.f;
#pragma unroll 8
        for (int k = 0; k < SDIM; k += 4) {
            a0 = fmaf(sA[k + 0], a2w[(k + 0) * 64 + i], a0);
            a1 = fmaf(sA[k + 1], a2w[(k + 1) * 64 + i], a1);
            a2 = fmaf(sA[k + 2], a2w[(k + 2) * 64 + i], a2);
            a3 = fmaf(sA[k + 3], a2w[(k + 3) * 64 + i], a3);
        }
        sc2[i] = a2b[i] + ((a0 + a1) + (a2 + a3));
    }
    __syncthreads();

    if (t < 64) {
        float a0 = 0.f, a1 = 0.f, a2 = 0.f, a3 = 0.f;
#pragma unroll 4
        for (int i = 0; i < 32; i += 4) {
            const float v0 = m0w[(i + 0) * 64 + t] * sc0[i + 0];
            const float v1 = m0w[(i + 1) * 64 + t] * sc0[i + 1];
            const float v2 = m0w[(i + 2) * 64 + t] * sc0[i + 2];
            const float v3 = m0w[(i + 3) * 64 + t] * sc0[i + 3];
            a0 = fmaf(v0, v0, a0);
            a1 = fmaf(v1, v1, a1);
            a2 = fmaf(v2, v2, a2);
            a3 = fmaf(v3, v3, a3);
        }
        d0[t] = rsqrtf(((a0 + a1) + (a2 + a3)) + 1e-8f);
    } else if (t < 128) {
        const int j = t - 64;
        float a0 = 0.f, a1 = 0.f, a2 = 0.f, a3 = 0.f;
#pragma unroll 4
        for (int i = 0; i < 64; i += 4) {
            const float v0 = m1w[(i + 0) * 64 + j] * sc1[i + 0];
            const float v1 = m1w[(i + 1) * 64 + j] * sc1[i + 1];
            const float v2 = m1w[(i + 2) * 64 + j] * sc1[i + 2];
            const float v3 = m1w[(i + 3) * 64 + j] * sc1[i + 3];
            a0 = fmaf(v0, v0, a0);
            a1 = fmaf(v1, v1, a1);
            a2 = fmaf(v2, v2, a2);
            a3 = fmaf(v3, v3, a3);
        }
        d1[j] = rsqrtf(((a0 + a1) + (a2 + a3)) + 1e-8f);
    } else if (t < 131) {
        const int j = t - 128;
        float a0 = 0.f, a1 = 0.f, a2 = 0.f, a3 = 0.f;
#pragma unroll 4
        for (int i = 0; i < 64; i += 4) {
            const float v0 = m2w[(i + 0) * 3 + j] * sc2[i + 0];
            const float v1 = m2w[(i + 1) * 3 + j] * sc2[i + 1];
            const float v2 = m2w[(i + 2) * 3 + j] * sc2[i + 2];
            const float v3 = m2w[(i + 3) * 3 + j] * sc2[i + 3];
            a0 = fmaf(v0, v0, a0);
            a1 = fmaf(v1, v1, a1);
            a2 = fmaf(v2, v2, a2);
            a3 = fmaf(v3, v3, a3);
        }
        d2[j] = rsqrtf(((a0 + a1) + (a2 + a3)) + 1e-8f);
    }
    __syncthreads();

    for (int e = t; e < 2048; e += 256) {
        const int i = e >> 6, j = e & 63;
        wl0[e] = m0w[e] * sc0[i] * d0[j] * modv[i];
    }
    for (int e = t; e < 4096; e += 256) {
        const int i = e >> 6, j = e & 63;
        wl1[e] = m1w[e] * sc1[i] * d1[j];
    }
    for (int e = t; e < 1024; e += 256) {
        const int i = e >> 4, j = e & 15;
        wl2[e] = (j < 3) ? m2w[i * 3 + j] * sc2[i] * d2[j] : 0.0f;
    }
    __syncthreads();

    // Pack Wᵀ A-fragments (A[row=lane&15][k=8*(lane>>4)+e], R5-verified layout),
    // hi/lo split, with the output-channel permutation ch(m, row).
    ushort_t* outb = wsf + b * BSTRIDE;
    for (int s = t; s < 896; s += 256) {
        const int f = s >> 6, lane = s & 63;
        const int gg = lane >> 4, cc = lane & 15;   // cc = A row, k = 8*gg+e
        bf16x8 hv, lv;
#pragma unroll
        for (int e = 0; e < 8; ++e) {
            float wv;
            if (f < 4) {
                const int m = f;
                const int ch = 8 * (cc >> 2) + (cc & 3) + 4 * (m & 1) + 32 * (m >> 1);
                wv = wl0[(8 * gg + e) * 64 + ch];
            } else if (f < 12) {
                const int m = (f - 4) >> 1, kf = (f - 4) & 1;
                const int ch = 8 * (cc >> 2) + (cc & 3) + 4 * (m & 1) + 32 * (m >> 1);
                wv = wl1[(32 * kf + 8 * gg + e) * 64 + ch];
            } else {
                const int kf = f - 12;
                wv = wl2[(32 * kf + 8 * gg + e) * 16 + cc];   // out=cc, 0-padded cc>=3
            }
            const ushort_t hh = f2bf(wv);
            hv[e] = (short)hh;
            lv[e] = (short)f2bf(wv - bf2f(hh));
        }
        *(bf16x8*)(outb + f * 1024 + lane * 8) = hv;
        *(bf16x8*)(outb + f * 1024 + 512 + lane * 8) = lv;
    }
}

// Swapped-operand MFMA chain: D = Wᵀ·Hᵀ per layer. No LDS, no barriers —
// layer transitions are pure in-register repacks (channel permutation makes
// each layer's output lane-local for the next layer's B-frag). [R12: passed]
__global__ __launch_bounds__(256) void k_main(
    const float* __restrict__ base_tables,
    const ushort_t* __restrict__ wsf,
    const float* __restrict__ m0b,
    const float* __restrict__ m1b,
    const float* __restrict__ m2b,
    float* __restrict__ out,
    ResPack rp)
{
    const int t = threadIdx.x;
    const int w = t >> 6;
    const int l = t & 63;
    const int g = l >> 4;
    const int c = l & 15;
    const int tile_base = blockIdx.x * 64 + w * 16;

    // ---- features: lane (g,c) needs levels 4g..4g+3 of pixel tile_base+c.
    // rf_hi = B-frag for layer 0: B[k=8g+e][col=c] = feat[c][8g+e]. (R5-verified)
    const int apx = tile_base + c;
    const float cx = ((float)(apx & 255) + 0.5f) * (1.0f / 256.0f);
    const float cy = ((float)(apx >> 8) + 0.5f) * (1.0f / 256.0f);
    bf16x8 rf_hi;
#pragma unroll
    for (int d = 0; d < 4; ++d) {
        float r1 = rp.rm1[d];
        r1 = (g == 1) ? rp.rm1[4 + d] : r1;
        r1 = (g == 2) ? rp.rm1[8 + d] : r1;
        r1 = (g == 3) ? rp.rm1[12 + d] : r1;
        const float sx = cx * r1, sy = cy * r1;
        const float pxf = floorf(sx), pyf = floorf(sy);
        const float fx = sx - pxf, fy = sy - pyf;
        const unsigned x0 = (unsigned)pxf, y0 = (unsigned)pyf;
        const unsigned x1 = x0 + 1u, y1 = y0 + 1u;
        const unsigned hy0 = y0 * P2H, hy1 = y1 * P2H;
        const float2* tab = reinterpret_cast<const float2*>(base_tables) + ((4 * g + d) << 14);
        const float2 f00 = tab[(x0 ^ hy0) & (TSZ - 1)];
        const float2 f01 = tab[(x0 ^ hy1) & (TSZ - 1)];
        const float2 f10 = tab[(x1 ^ hy0) & (TSZ - 1)];
        const float2 f11 = tab[(x1 ^ hy1) & (TSZ - 1)];
        const float w00 = (1.0f - fx) * (1.0f - fy);
        const float w01 = (1.0f - fx) * fy;
        const float w10 = fx * (1.0f - fy);
        const float w11 = fx * fy;
        const float v0 = w00 * f00.x + w01 * f01.x + w10 * f10.x + w11 * f11.x;
        const float v1 = w00 * f00.y + w01 * f01.y + w10 * f10.y + w11 * f11.y;
        rf_hi[2 * d]     = (short)f2bf(v0);
        rf_hi[2 * d + 1] = (short)f2bf(v1);
    }

    // ---- biases at permuted channel ch(m,4g+q) = 8g+q+4(m&1)+32(m>>1)
    float b0v[4][4], b1v[4][4];
#pragma unroll
    for (int m = 0; m < 4; ++m)
#pragma unroll
        for (int q = 0; q < 4; ++q) {
            const int ch = 8 * g + q + 4 * (m & 1) + 32 * (m >> 1);
            b0v[m][q] = m0b[ch];
            b1v[m][q] = m1b[ch];
        }
    const floatx4 acc2init = (g == 0)
        ? (floatx4){ m2b[0], m2b[1], m2b[2], 0.0f }
        : (floatx4){ 0.0f, 0.0f, 0.0f, 0.0f };

#pragma unroll 1
    for (int b = 0; b < BATCH; ++b) {
        const ushort_t* F = wsf + b * BSTRIDE + l * 8;
#define LDF(fi, which) (*(const bf16x8*)(F + (fi) * 1024 + (which) * 512))

        // ---- layer 0: D0_m = W0ᵀ_m · featᵀ  (K=32; W hi+lo, act hi)
        floatx4 acc0[4];
#pragma unroll
        for (int m = 0; m < 4; ++m) {
            acc0[m] = (floatx4){ b0v[m][0], b0v[m][1], b0v[m][2], b0v[m][3] };
            acc0[m] = __builtin_amdgcn_mfma_f32_16x16x32_bf16(LDF(m, 0), rf_hi, acc0[m], 0, 0, 0);
            acc0[m] = __builtin_amdgcn_mfma_f32_16x16x32_bf16(LDF(m, 1), rf_hi, acc0[m], 0, 0, 0);
        }
        // lrelu + repack: lane holds h0[c][8g+e] (m 0..1) and h0[c][32+8g+e] (m 2..3)
        bf16x8 h1f0, h1f1;
#pragma unroll
        for (int e = 0; e < 8; ++e) {
            h1f0[e] = (short)f2bf(lrelu(acc0[e >> 2][e & 3]));
            h1f1[e] = (short)f2bf(lrelu(acc0[2 + (e >> 2)][e & 3]));
        }

        // ---- layer 1: D1_m = W1ᵀ_m · h0ᵀ  (K=64 = 2 kfrags)
        floatx4 acc1[4];
#pragma unroll
        for (int m = 0; m < 4; ++m) {
            acc1[m] = (floatx4){ b1v[m][0], b1v[m][1], b1v[m][2], b1v[m][3] };
            acc1[m] = __builtin_amdgcn_mfma_f32_16x16x32_bf16(LDF(4 + 2 * m, 0), h1f0, acc1[m], 0, 0, 0);
            acc1[m] = __builtin_amdgcn_mfma_f32_16x16x32_bf16(LDF(4 + 2 * m, 1), h1f0, acc1[m], 0, 0, 0);
            acc1[m] = __builtin_amdgcn_mfma_f32_16x16x32_bf16(LDF(5 + 2 * m, 0), h1f1, acc1[m], 0, 0, 0);
            acc1[m] = __builtin_amdgcn_mfma_f32_16x16x32_bf16(LDF(5 + 2 * m, 1), h1f1, acc1[m], 0, 0, 0);
        }
        bf16x8 h2f0, h2f1;
#pragma unroll
        for (int e = 0; e < 8; ++e) {
            h2f0[e] = (short)f2bf(lrelu(acc1[e >> 2][e & 3]));
            h2f1[e] = (short)f2bf(lrelu(acc1[2 + (e >> 2)][e & 3]));
        }

        // ---- layer 2: D2 = W2ᵀ · h1ᵀ (rows 0..2 real, rest zero-padded)
        floatx4 acc2 = acc2init;
        acc2 = __builtin_amdgcn_mfma_f32_16x16x32_bf16(LDF(12, 0), h2f0, acc2, 0, 0, 0);
        acc2 = __builtin_amdgcn_mfma_f32_16x16x32_bf16(LDF(12, 1), h2f0, acc2, 0, 0, 0);
        acc2 = __builtin_amdgcn_mfma_f32_16x16x32_bf16(LDF(13, 0), h2f1, acc2, 0, 0, 0);
        acc2 = __builtin_amdgcn_mfma_f32_16x16x32_bf16(LDF(13, 1), h2f1, acc2, 0, 0, 0);

        // store: lane (0,c) holds out channels 0..2 (rows q) of pixel tile_base+c
        if (g == 0) {
            out[(b * 3 + 0) * NPIX + tile_base + c] = acc2[0];
            out[(b * 3 + 1) * NPIX + tile_base + c] = acc2[1];
            out[(b * 3 + 2) * NPIX + tile_base + c] = acc2[2];
        }
#undef LDF
    }
}

extern "C" void kernel_launch(void* const* d_in, const int* in_sizes, int n_in,
                              void* d_out, int out_size, void* d_ws, size_t ws_size,
                              hipStream_t stream) {
    const float* z    = (const float*)d_in[0];
    const float* w1   = (const float*)d_in[1];
    const float* b1   = (const float*)d_in[2];
    const float* w2   = (const float*)d_in[3];
    const float* b2   = (const float*)d_in[4];
    const float* w3   = (const float*)d_in[5];
    const float* b3   = (const float*)d_in[6];
    const float* bt   = (const float*)d_in[7];
    const float* genw = (const float*)d_in[8];
    const float* a0w  = (const float*)d_in[9];
    const float* a0b  = (const float*)d_in[10];
    const float* m0w  = (const float*)d_in[11];
    const float* m0b  = (const float*)d_in[12];
    const float* a1w  = (const float*)d_in[13];
    const float* a1b  = (const float*)d_in[14];
    const float* m1w  = (const float*)d_in[15];
    const float* m1b  = (const float*)d_in[16];
    const float* a2w  = (const float*)d_in[17];
    const float* a2b  = (const float*)d_in[18];
    const float* m2w  = (const float*)d_in[19];
    const float* m2b  = (const float*)d_in[20];
    ushort_t* wsf = (ushort_t*)d_ws;
    float* out = (float*)d_out;

    ResPack rp;
    const double bfac = exp((log(256.0) - log(16.0)) / 15.0);
    for (int lv = 0; lv < LVL; ++lv) {
        const double v = floor(16.0 * pow(bfac, (double)lv));
        rp.rm1[lv] = (float)v - 1.0f;
    }

    hipLaunchKernelGGL(k_setup, dim3(BATCH), dim3(256), 0, stream,
                       z, w1, b1, w2, b2, w3, b3, genw,
                       a0w, a0b, m0w, a1w, a1b, m1w, a2w, a2b, m2w, wsf);

    hipLaunchKernelGGL(k_main, dim3(NPIX / 64), dim3(256), 0, stream,
                       bt, wsf, m0b, m1b, m2b, out, rp);
}